// Round 3
// baseline (67.520 us; speedup 1.0000x reference)
//
#include <hip/hip_runtime.h>

#define BATCH 8
#define CIN   64
#define COUT  64
#define LEN   16384
#define KS    5
#define PADW  2
#define LP    (LEN + 2*PADW)
#define TT    64
#define NK8   40            // 16B chunks along K (320 bf16 * 2B / 16B)
#define XW    96            // staged xp-window rows
#define XM    14            // window = [t0-XM, t0-XM+XW)

typedef __attribute__((ext_vector_type(8)))  short  short8;
typedef __attribute__((ext_vector_type(16))) float  f32x16;
typedef __attribute__((ext_vector_type(8)))  unsigned short ushort8;

__device__ __forceinline__ unsigned short bf16r(float f) {
    unsigned u = __builtin_bit_cast(unsigned, f);
    u += 0x7FFF + ((u >> 16) & 1);          // RNE
    return (unsigned short)(u >> 16);
}

__device__ __forceinline__ int reflmap(int s) {  // xp index -> x index
    return (s < PADW) ? (PADW - s) : ((s < LEN + PADW) ? (s - PADW) : (2*LEN - s));
}

// Pre-arrange W (f32 [o][c][k]) into bf16 A-fragment order for
// mfma_f32_32x32x16_bf16, K-dim k-major: ck' = k*64 + c.
__global__ void wfrag_kernel(const float* __restrict__ w, unsigned short* __restrict__ wf) {
    int el = blockIdx.x * 256 + threadIdx.x;     // 20480 total
    int bidx = el & 7;
    int lane = (el >> 3) & 63;
    int kk   = (el >> 9) % 20;
    int wm   = el / 10240;
    int o    = wm * 32 + (lane & 31);
    int ckp  = kk * 16 + ((lane >> 5) << 3) + bidx;
    int k    = ckp >> 6;
    int c    = ckp & 63;
    wf[el] = bf16r(w[(o * 64 + c) * 5 + k]);
}

__global__ __launch_bounds__(256) void deform_mfma_kernel(
    const float* __restrict__ x, const float* __restrict__ offs,
    const unsigned short* __restrict__ wf, const float* __restrict__ bias,
    float* __restrict__ out)
{
    __shared__ __align__(16) unsigned char   xtile[XW * 256];        // 24 KB [r][c] f32, XOR-swizzled
    __shared__ __align__(16) unsigned short  vlds[NK8 * 64 * 8];     // 40 KB [k8][t][8]

    const int tid = threadIdx.x;
    const int bt  = blockIdx.x;
    const int b   = bt >> 8;
    const int t0  = (bt & 255) * TT;
    const int tl  = tid & 63;
    const int w   = tid >> 6;
    const int t   = t0 + tl;
    const int S0  = t0 - XM;

    // ---- stage x window into LDS, transposed [r][c], swizzled ----
    const float* xb0 = x + (size_t)b * CIN * LEN;
    #pragma unroll
    for (int rep = 0; rep < 24; ++rep) {
        int idx = rep * 256 + tid;         // 6144 elements
        int c = idx / XW;                  // const divisor -> magic mul
        int r = idx - c * XW;
        int s = S0 + r;
        s = min(max(s, 0), LP - 1);
        float val = xb0[(size_t)c * LEN + reflmap(s)];
        int byte = (r * 256 + c * 4) ^ ((r & 7) << 4);
        *(float*)(xtile + byte) = val;
    }

    // ---- per-thread (i0, frac) for k = 0..4 ----
    int i0r[KS]; float frr[KS];
    #pragma unroll
    for (int k = 0; k < KS; ++k) {
        float off = offs[(size_t)(b * LEN + t) * KS + k];
        float T = (float)(t + k) + off;
        T = fminf(fmaxf(T, 0.0f), (float)(LP - 1));
        int i0 = (int)floorf(T);
        i0 = min(i0, LP - 2); i0 = max(i0, 0);
        i0r[k] = i0;
        frr[k] = T - (float)i0;
    }
    __syncthreads();

    // ---- gather + lerp + bf16 pack into vlds[k8][t] ----
    #pragma unroll
    for (int it = 0; it < 10; ++it) {
        const int k  = it >> 1;                        // compile-time
        const int c0 = (w + ((it & 1) << 2)) << 3;     // 0,8,...,56
        const int i0 = i0r[k];
        const float f = frr[k];
        const int r0 = i0 - S0;
        float4 g0a, g0b, g1a, g1b;
        if ((unsigned)r0 <= (unsigned)(XW - 2)) {
            const int r1 = r0 + 1;
            const int b0 = r0 * 256 + c0 * 4;
            const int b1 = r1 * 256 + c0 * 4;
            const int x0 = (r0 & 7) << 4;
            const int x1 = (r1 & 7) << 4;
            g0a = *(const float4*)(xtile + ( b0        ^ x0));
            g0b = *(const float4*)(xtile + ((b0 + 16)  ^ x0));
            g1a = *(const float4*)(xtile + ( b1        ^ x1));
            g1b = *(const float4*)(xtile + ((b1 + 16)  ^ x1));
        } else {
            // out-of-window offset (|off| > ~13): global reflect fallback
            int j0 = reflmap(i0), j1 = reflmap(i0 + 1);
            const float* xc = xb0 + (size_t)c0 * LEN;
            g0a.x = xc[j0]; g1a.x = xc[j1]; xc += LEN;
            g0a.y = xc[j0]; g1a.y = xc[j1]; xc += LEN;
            g0a.z = xc[j0]; g1a.z = xc[j1]; xc += LEN;
            g0a.w = xc[j0]; g1a.w = xc[j1]; xc += LEN;
            g0b.x = xc[j0]; g1b.x = xc[j1]; xc += LEN;
            g0b.y = xc[j0]; g1b.y = xc[j1]; xc += LEN;
            g0b.z = xc[j0]; g1b.z = xc[j1]; xc += LEN;
            g0b.w = xc[j0]; g1b.w = xc[j1];
        }
        ushort8 pk;
        pk[0] = bf16r(fmaf(f, g1a.x - g0a.x, g0a.x));
        pk[1] = bf16r(fmaf(f, g1a.y - g0a.y, g0a.y));
        pk[2] = bf16r(fmaf(f, g1a.z - g0a.z, g0a.z));
        pk[3] = bf16r(fmaf(f, g1a.w - g0a.w, g0a.w));
        pk[4] = bf16r(fmaf(f, g1b.x - g0b.x, g0b.x));
        pk[5] = bf16r(fmaf(f, g1b.y - g0b.y, g0b.y));
        pk[6] = bf16r(fmaf(f, g1b.z - g0b.z, g0b.z));
        pk[7] = bf16r(fmaf(f, g1b.w - g0b.w, g0b.w));
        const int k8 = w + (it << 2);
        *(ushort8*)&vlds[(k8 * 64 + tl) * 8] = pk;
    }
    __syncthreads();

    // ---- MFMA: out[64cout x 64t], 4 waves x one 32x32 tile, K=320 ----
    const int lane = tid & 63;
    const int wm = w >> 1, wn = w & 1;
    f32x16 acc = {};
    const unsigned short* wfp = wf + ((size_t)(wm * 20) * 64 + lane) * 8;
    const int boff = (((lane >> 5) * 64) + wn * 32 + (lane & 31)) * 8;
    #pragma unroll
    for (int kk = 0; kk < 20; ++kk) {
        short8 a  = *(const short8*)&wfp[kk * 512];
        short8 bf = *(const short8*)&vlds[boff + kk * 1024];
        acc = __builtin_amdgcn_mfma_f32_32x32x16_bf16(a, bf, acc, 0, 0, 0);
    }

    // ---- epilogue: col=lane&31, row=(r&3)+8*(r>>2)+4*(lane>>5) ----
    const int tc = t0 + wn * 32 + (lane & 31);
    const int rbase = 4 * (lane >> 5);
    #pragma unroll
    for (int r = 0; r < 16; ++r) {
        int row = (r & 3) + 8 * (r >> 2) + rbase;
        int o = wm * 32 + row;
        out[((size_t)(b * COUT + o)) * LEN + tc] = acc[r] + bias[o];
    }
}

extern "C" void kernel_launch(void* const* d_in, const int* in_sizes, int n_in,
                              void* d_out, int out_size, void* d_ws, size_t ws_size,
                              hipStream_t stream) {
    const float* x    = (const float*)d_in[0];
    const float* offs = (const float*)d_in[1];
    const float* w    = (const float*)d_in[2];
    const float* bias = (const float*)d_in[3];
    float* out = (float*)d_out;
    unsigned short* wf = (unsigned short*)d_ws;   // 40960 B

    wfrag_kernel<<<80, 256, 0, stream>>>(w, wf);
    deform_mfma_kernel<<<BATCH * (LEN / TT), 256, 0, stream>>>(x, offs, wf, bias, out);
}

// Round 5
// 42.861 us; speedup vs baseline: 1.5753x; 1.5753x over previous
//
#include <hip/hip_runtime.h>

#define BATCH 8
#define CIN   64
#define COUT  64
#define LEN   16384
#define KS    5
#define PADW  2
#define LP    (LEN + 2*PADW)
#define TT    64
#define XW    96            // staged window rows (padded coords)
#define XM    14            // window start S0 = t0 - XM (padded coords)
#define VK8   24            // vbuf capacity in 16B k-chunks

typedef __attribute__((ext_vector_type(8)))  short  short8;
typedef __attribute__((ext_vector_type(16))) float  f32x16;
typedef __attribute__((ext_vector_type(8)))  unsigned short ushort8;

__device__ __forceinline__ unsigned short bf16r(float f) {
    unsigned u = __builtin_bit_cast(unsigned, f);
    u += 0x7FFF + ((u >> 16) & 1);          // RNE
    return (unsigned short)(u >> 16);
}

__device__ __forceinline__ int reflmap(int s) {  // padded idx -> x idx
    return (s < PADW) ? (PADW - s) : ((s < LEN + PADW) ? (s - PADW) : (2*LEN - s));
}

// Pre-arrange W (f32 [o][c][k]) -> bf16 A-frags for mfma_f32_32x32x16_bf16,
// K-dim k-major: ck' = k*64 + c.  wf[((wm*20 + kk)*64 + lane)*8 + bidx]
__global__ void wfrag_kernel(const float* __restrict__ w, unsigned short* __restrict__ wf) {
    int el = blockIdx.x * 256 + threadIdx.x;     // 20480 total
    int bidx = el & 7;
    int lane = (el >> 3) & 63;
    int kk   = (el >> 9) % 20;
    int wm   = el / 10240;
    int o    = wm * 32 + (lane & 31);
    int ckp  = kk * 16 + ((lane >> 5) << 3) + bidx;
    int k    = ckp >> 6;
    int c    = ckp & 63;
    wf[el] = bf16r(w[(o * 64 + c) * 5 + k]);
}

__global__ __launch_bounds__(256) void deform_mfma_kernel(
    const float* __restrict__ x, const float* __restrict__ offs,
    const unsigned short* __restrict__ wf, const float* __restrict__ bias,
    float* __restrict__ out)
{
    __shared__ __align__(16) float          xt[CIN * XW];          // 24 KB [c][r]
    __shared__ __align__(16) unsigned short vbuf[VK8 * 64 * 8];    // 24 KB [k8][t][8]

    const int tid = threadIdx.x;
    const int bt  = blockIdx.x;
    const int b   = bt >> 8;
    const int t0  = (bt & 255) * TT;
    const int tl  = tid & 63;
    const int w   = tid >> 6;
    const int t   = t0 + tl;
    const int S0  = t0 - XM;                 // padded coord of xt row 0

    const float* xb0 = x + (size_t)b * CIN * LEN;

    // ---- stage xp window into xt[c][r] (xt[c][r] = xp[S0+r]) ----
    if (S0 >= PADW && S0 - PADW + XW <= LEN) {
        // interior: xp[S0+r] = x[S0-PADW+r]; base S0-PADW = t0-16 -> 16B aligned
        const float* src0 = xb0 + (S0 - PADW);
        #pragma unroll
        for (int rep = 0; rep < 6; ++rep) {
            int cid = rep * 256 + tid;          // 0..1535
            int c = cid / 24, q = cid - c * 24;
            float4 vv = *(const float4*)(src0 + (size_t)c * LEN + 4 * q);
            *(float4*)&xt[c * XW + 4 * q] = vv;
        }
    } else {                                     // edge tiles: reflect per element
        #pragma unroll
        for (int rep = 0; rep < 24; ++rep) {
            int idx = rep * 256 + tid;          // 0..6143
            int c = idx / XW, r = idx - c * XW;
            int s = S0 + r;
            s = min(max(s, 0), LP - 1);
            xt[c * XW + r] = xb0[(size_t)c * LEN + reflmap(s)];
        }
    }

    // ---- per-thread (i0, frac), k = 0..4 (padded coords) ----
    int i0r[KS]; float frr[KS];
    #pragma unroll
    for (int k = 0; k < KS; ++k) {
        float off = offs[(size_t)(b * LEN + t) * KS + k];
        float T = (float)(t + k) + off;
        T = fminf(fmaxf(T, 0.0f), (float)(LP - 1));
        int i0 = (int)floorf(T);
        i0 = min(i0, LP - 2); i0 = max(i0, 0);
        i0r[k] = i0;
        frr[k] = T - (float)i0;
    }
    __syncthreads();

    f32x16 acc = {};
    const int lane = tl;
    const int wm = w >> 1, wn = w & 1;
    const unsigned short* wfp = wf + ((size_t)(wm * 20) * 64 + lane) * 8;
    const int boff = (((lane >> 5) * 64) + wn * 32 + (lane & 31)) * 8;

    #pragma unroll
    for (int ph = 0; ph < 2; ++ph) {
        if (ph) __syncthreads();                 // vbuf reuse fence
        const int itlo = ph ? 6 : 0;
        const int itn  = ph ? 4 : 6;             // compile-time (ph unrolled)
        #pragma unroll
        for (int ii = 0; ii < itn; ++ii) {
            const int it = itlo + ii;
            const int k  = it >> 1;              // compile-time
            const int c0 = (w + ((it & 1) << 2)) << 3;
            const int i0 = i0r[k];
            const float f = frr[k];
            const int r0 = i0 - S0;
            float g0v[8], g1v[8];
            if ((unsigned)r0 <= (unsigned)(XW - 2)) {
                const int base = c0 * XW + r0;
                #pragma unroll
                for (int e = 0; e < 8; ++e) {    // ds_read2_b32 pairs, bank = r0&31
                    g0v[e] = xt[base + e * XW];
                    g1v[e] = xt[base + e * XW + 1];
                }
            } else {                             // offset beyond window: rare
                int j0 = reflmap(i0), j1 = reflmap(i0 + 1);
                const float* xc = xb0 + (size_t)c0 * LEN;
                #pragma unroll
                for (int e = 0; e < 8; ++e) {
                    g0v[e] = xc[j0]; g1v[e] = xc[j1]; xc += LEN;
                }
            }
            ushort8 pk;
            #pragma unroll
            for (int e = 0; e < 8; ++e)
                pk[e] = bf16r(fmaf(f, g1v[e] - g0v[e], g0v[e]));
            *(ushort8*)&vbuf[((w + (ii << 2)) * 64 + tl) * 8] = pk;  // vbuf chunk = global-24*ph
        }
        __syncthreads();
        const int kklo = ph ? 12 : 0;
        const int kkn  = ph ? 8 : 12;
        #pragma unroll
        for (int jj = 0; jj < kkn; ++jj) {
            const int kk = kklo + jj;
            short8 a  = *(const short8*)&wfp[kk * 512];
            short8 bf = *(const short8*)&vbuf[boff + jj * 1024];   // chunks 2jj+h (+24*ph global)
            acc = __builtin_amdgcn_mfma_f32_32x32x16_bf16(a, bf, acc, 0, 0, 0);
        }
    }

    // ---- epilogue: col=lane&31, row=(r&3)+8*(r>>2)+4*(lane>>5) ----
    const int tc = t0 + wn * 32 + (lane & 31);
    const int rbase = 4 * (lane >> 5);
    #pragma unroll
    for (int r = 0; r < 16; ++r) {
        int row = (r & 3) + 8 * (r >> 2) + rbase;
        int o = wm * 32 + row;
        out[((size_t)(b * COUT + o)) * LEN + tc] = acc[r] + bias[o];
    }
}

extern "C" void kernel_launch(void* const* d_in, const int* in_sizes, int n_in,
                              void* d_out, int out_size, void* d_ws, size_t ws_size,
                              hipStream_t stream) {
    const float* x    = (const float*)d_in[0];
    const float* offs = (const float*)d_in[1];
    const float* w    = (const float*)d_in[2];
    const float* bias = (const float*)d_in[3];
    float* out = (float*)d_out;
    unsigned short* wf = (unsigned short*)d_ws;   // 40960 B

    wfrag_kernel<<<80, 256, 0, stream>>>(w, wf);
    deform_mfma_kernel<<<BATCH * (LEN / TT), 256, 0, stream>>>(x, offs, wf, bias, out);
}

// Round 6
// 39.824 us; speedup vs baseline: 1.6955x; 1.0763x over previous
//
#include <hip/hip_runtime.h>

#define BATCH 8
#define CIN   64
#define COUT  64
#define LEN   16384
#define KS    5
#define PADW  2
#define LP    (LEN + 2*PADW)
#define TT    64
#define XW    96            // staged window rows (padded coords)
#define XST   97            // xt row stride in words (97 % 32 = 1 -> bank spread)
#define XM    14            // window start S0 = t0 - XM

typedef __attribute__((ext_vector_type(8)))  short short8;
typedef __attribute__((ext_vector_type(4)))  float f32x4;
typedef __attribute__((ext_vector_type(8)))  unsigned short ushort8;

__device__ __forceinline__ unsigned short bf16r(float f) {
    unsigned u = __builtin_bit_cast(unsigned, f);
    u += 0x7FFF + ((u >> 16) & 1);          // RNE
    return (unsigned short)(u >> 16);
}

__device__ __forceinline__ int reflmap(int s) {  // padded idx -> x idx
    return (s < PADW) ? (PADW - s) : ((s < LEN + PADW) ? (s - PADW) : (2*LEN - s));
}

// W (f32 [o][c][k]) -> bf16 A-frags for mfma_f32_16x16x32_bf16, K k-major
// (ck' = ktap*64 + c).  wf[((ot*10 + kk)*64 + lane)*8 + bidx]
//   A[row=ot*16+(lane&15)][kq=(lane>>4)*8+bidx], global ck' = kk*32 + kq
__global__ void wfrag_kernel(const float* __restrict__ w, unsigned short* __restrict__ wf) {
    int el = blockIdx.x * 256 + threadIdx.x;          // 20480 total
    int bidx = el & 7;
    int lane = (el >> 3) & 63;
    int kk   = (el >> 9) % 10;
    int ot   = el / 5120;
    int o    = ot * 16 + (lane & 15);
    int kg   = kk * 32 + ((lane >> 4) << 3) + bidx;   // ck' 0..319
    int ktap = kg >> 6;
    int c    = kg & 63;
    wf[el] = bf16r(w[(o * 64 + c) * 5 + ktap]);
}

__global__ __launch_bounds__(256) void deform_mfma_kernel(
    const float* __restrict__ x, const float* __restrict__ offs,
    const unsigned short* __restrict__ wf, const float* __restrict__ bias,
    float* __restrict__ out)
{
    __shared__ float xt[CIN * XST];          // 24832 B

    const int tid = threadIdx.x;
    const int bt  = blockIdx.x;
    const int b   = bt >> 8;
    const int t0  = (bt & 255) * TT;
    const int w   = tid >> 6;
    const int lane = tid & 63;
    const int col = lane & 15;
    const int s   = lane >> 4;               // chunk-slot / A-row group
    const int tc  = t0 + w * 16 + col;       // this thread's output column
    const int S0  = t0 - XM;                 // padded coord of xt row 0

    const float* xb0 = x + (size_t)b * CIN * LEN;

    // ---- stage xp window into xt[c][r], stride 97 (xt[c*XST+r] = xp[S0+r]) ----
    if (S0 >= PADW && S0 - PADW + XW <= LEN) {
        const float* src0 = xb0 + (S0 - PADW);       // t0-16: 16B aligned
        #pragma unroll
        for (int rep = 0; rep < 6; ++rep) {
            int cid = rep * 256 + tid;               // 0..1535
            int c = cid / 24, q = cid - c * 24;
            float4 vv = *(const float4*)(src0 + (size_t)c * LEN + 4 * q);
            float* dst = &xt[c * XST + 4 * q];
            dst[0] = vv.x; dst[1] = vv.y; dst[2] = vv.z; dst[3] = vv.w;
        }
    } else {                                         // 2 edge tiles per row
        #pragma unroll
        for (int rep = 0; rep < 24; ++rep) {
            int idx = rep * 256 + tid;               // 0..6143
            int c = idx / XW, r = idx - c * XW;
            int sp = S0 + r;
            sp = min(max(sp, 0), LP - 1);
            xt[c * XST + r] = xb0[(size_t)c * LEN + reflmap(sp)];
        }
    }

    // ---- per-thread (i0, frac) for its own column tc, k = 0..4 ----
    int i0r[KS]; float frr[KS]; int r0r[KS];
    bool fast = true;
    #pragma unroll
    for (int k = 0; k < KS; ++k) {
        float off = offs[(size_t)(b * LEN + tc) * KS + k];
        float T = (float)(tc + k) + off;
        T = fminf(fmaxf(T, 0.0f), (float)(LP - 1));
        int i0 = (int)floorf(T);
        i0 = min(i0, LP - 2); i0 = max(i0, 0);
        i0r[k] = i0;
        frr[k] = T - (float)i0;
        r0r[k] = i0 - S0;
        fast = fast && ((unsigned)(i0 - S0) <= (unsigned)(XW - 2));
    }
    __syncthreads();

    f32x4 acc0 = {}, acc1 = {}, acc2 = {}, acc3 = {};
    const unsigned short* wfl = wf + (size_t)lane * 8;

    // Per kk: gather this lane's B-frag (chunk 4kk+s of column tc) into regs,
    // then 4 MFMAs (one per C_out row-tile). k-tap = kk>>1 is compile-time.
#define GSTEP(kk, CHECKED)                                                     \
    {                                                                          \
        const int k  = (kk) >> 1;                                              \
        const int c0 = ((((kk) & 1) << 2) + s) << 3;                           \
        const float f = frr[k];                                                \
        ushort8 pk;                                                            \
        if (!(CHECKED) || (unsigned)r0r[k] <= (unsigned)(XW - 2)) {            \
            const float* p = &xt[c0 * XST + r0r[k]];                           \
            _Pragma("unroll")                                                  \
            for (int e = 0; e < 8; ++e) {                                      \
                float g0 = p[0], g1 = p[1];                                    \
                pk[e] = bf16r(fmaf(f, g1 - g0, g0));                           \
                p += XST;                                                      \
            }                                                                  \
        } else {                                                               \
            int j0 = reflmap(i0r[k]), j1 = reflmap(i0r[k] + 1);                \
            const float* xc = xb0 + (size_t)c0 * LEN;                          \
            _Pragma("unroll")                                                  \
            for (int e = 0; e < 8; ++e) {                                      \
                float g0 = xc[j0], g1 = xc[j1];                                \
                pk[e] = bf16r(fmaf(f, g1 - g0, g0));                           \
                xc += LEN;                                                     \
            }                                                                  \
        }                                                                      \
        short8 bv = __builtin_bit_cast(short8, pk);                            \
        short8 a0 = *(const short8*)&wfl[(0 * 10 + (kk)) * 512];               \
        short8 a1 = *(const short8*)&wfl[(1 * 10 + (kk)) * 512];               \
        short8 a2 = *(const short8*)&wfl[(2 * 10 + (kk)) * 512];               \
        short8 a3 = *(const short8*)&wfl[(3 * 10 + (kk)) * 512];               \
        acc0 = __builtin_amdgcn_mfma_f32_16x16x32_bf16(a0, bv, acc0, 0, 0, 0); \
        acc1 = __builtin_amdgcn_mfma_f32_16x16x32_bf16(a1, bv, acc1, 0, 0, 0); \
        acc2 = __builtin_amdgcn_mfma_f32_16x16x32_bf16(a2, bv, acc2, 0, 0, 0); \
        acc3 = __builtin_amdgcn_mfma_f32_16x16x32_bf16(a3, bv, acc3, 0, 0, 0); \
    }

    if (fast) {
        GSTEP(0,0) GSTEP(1,0) GSTEP(2,0) GSTEP(3,0) GSTEP(4,0)
        GSTEP(5,0) GSTEP(6,0) GSTEP(7,0) GSTEP(8,0) GSTEP(9,0)
    } else {
        GSTEP(0,1) GSTEP(1,1) GSTEP(2,1) GSTEP(3,1) GSTEP(4,1)
        GSTEP(5,1) GSTEP(6,1) GSTEP(7,1) GSTEP(8,1) GSTEP(9,1)
    }
#undef GSTEP

    // ---- epilogue: C/D col=lane&15 (=tc), row=(lane>>4)*4+r  (o within tile) ----
    #pragma unroll
    for (int ot = 0; ot < 4; ++ot) {
        const f32x4 a = (ot == 0) ? acc0 : (ot == 1) ? acc1 : (ot == 2) ? acc2 : acc3;
        #pragma unroll
        for (int r = 0; r < 4; ++r) {
            int o = ot * 16 + s * 4 + r;
            out[((size_t)(b * COUT + o)) * LEN + tc] = a[r] + bias[o];
        }
    }
}

extern "C" void kernel_launch(void* const* d_in, const int* in_sizes, int n_in,
                              void* d_out, int out_size, void* d_ws, size_t ws_size,
                              hipStream_t stream) {
    const float* x    = (const float*)d_in[0];
    const float* offs = (const float*)d_in[1];
    const float* w    = (const float*)d_in[2];
    const float* bias = (const float*)d_in[3];
    float* out = (float*)d_out;
    unsigned short* wf = (unsigned short*)d_ws;   // 40960 B

    wfrag_kernel<<<80, 256, 0, stream>>>(w, wf);
    deform_mfma_kernel<<<BATCH * (LEN / TT), 256, 0, stream>>>(x, offs, wf, bias, out);
}